// Round 5
// baseline (312.888 us; speedup 1.0000x reference)
//
#include <hip/hip_runtime.h>

// Hadamard transform along C of NCHW f32 tensor:
// y[b,:,s] = (H1024 @ pad1024(x[b,:,s]))[:768] / 32,  H1024 = H32 (x) H32, c = 32*i + j.
//
// v3 (resubmit x2; rounds 3-4 were broker timeouts, kernel never ran):
// occupancy-first. v2 held 64 floats of a[] across both LDS rounds ->
// ~110 total regs (AGPR overflow) -> 16 waves/CU -> latency-bound at 2.4 TB/s.
// Now: 768 threads, scalar f32 lanes (32 lanes x 4B = 128B segments),
// a[32] = 32 floats, asymmetric q-rounds (24 then 8) so only a[24..31]
// (8 floats) survives into round-0 phase 2. Round 1 uses 3-way redundant
// compute so no thread idles. LDS 74.3KB -> 2 blocks/CU = 24 waves (75%).

#define NSPAT 3136            // 56*56
#define TS    32              // spatial tile per block
#define STQ   33              // LDS q-stride (floats), odd
#define STI   793             // LDS i-stride (floats) = 24*STQ + 1, odd

// scalar float FWHT stage, 32-entry array
#define FWHT_STAGE1(arr, D)                                  \
    _Pragma("unroll")                                        \
    for (int _b = 0; _b < 32; _b += 2 * (D)) {               \
        _Pragma("unroll")                                    \
        for (int _k = 0; _k < (D); ++_k) {                   \
            float _t = arr[_b + _k];                         \
            arr[_b + _k]       = _t + arr[_b + _k + (D)];    \
            arr[_b + _k + (D)] = _t - arr[_b + _k + (D)];    \
        }                                                    \
    }

#define FWHT32_1(arr)      \
    FWHT_STAGE1(arr, 16)   \
    FWHT_STAGE1(arr, 8)    \
    FWHT_STAGE1(arr, 4)    \
    FWHT_STAGE1(arr, 2)    \
    FWHT_STAGE1(arr, 1)

__global__ __launch_bounds__(768, 6)
void hadamard_c768_kernel(const float* __restrict__ x, float* __restrict__ y) {
    __shared__ float lds[24 * STI];   // 19032 floats = 76128 B

    const int t   = threadIdx.x;
    const int bid = blockIdx.x;
    const int b   = bid / (NSPAT / TS);
    const int s0  = (bid % (NSPAT / TS)) * TS;
    const int base = b * 768 * NSPAT + s0;   // < 2^31, int ok

    const int g  = t >> 5;            // 0..23 : i-row (phase 1) / q (phase 2 r0)
    const int ln = t & 31;            // scalar lane along s

    // ---------------- Phase 1: load + FWHT over j ---------------------------
    float a[32];
    {
        const float* xb = x + base + ln;
        #pragma unroll
        for (int j = 0; j < 32; ++j)
            a[j] = xb[(32 * g + j) * NSPAT];
        FWHT32_1(a)
    }

    // ---------------- round 0: q = 0..23 ------------------------------------
    {
        float* p = lds + g * STI + ln;
        #pragma unroll
        for (int q = 0; q < 24; ++q)
            p[q * STQ] = a[q];
    }
    __syncthreads();

    float w[32];
    {
        const float* p = lds + g * STQ + ln;   // q = g, s = ln
        #pragma unroll
        for (int i = 0; i < 24; ++i)
            w[i] = p[i * STI];
    }
    __syncthreads();   // round-0 reads done -> region reusable

    // round-1 LDS writes (q 24..31 into slots 0..7); scheduler overlaps these
    // with the FWHT below.
    {
        float* p = lds + g * STI + ln;
        #pragma unroll
        for (int q = 0; q < 8; ++q)
            p[q * STQ] = a[24 + q];
    }

    // i-FWHT for round 0 (rows 24..31 known-zero) + store
    {
        #pragma unroll
        for (int i = 0; i < 8; ++i) {
            float tt  = w[i];
            w[i]      = tt + w[i + 16];
            w[i + 16] = tt - w[i + 16];
        }
        #pragma unroll
        for (int i = 8; i < 16; ++i)
            w[i + 16] = w[i];

        FWHT_STAGE1(w, 8)
        FWHT_STAGE1(w, 4)
        FWHT_STAGE1(w, 2)
        FWHT_STAGE1(w, 1)

        float* yb = y + base + ln;
        #pragma unroll
        for (int pp = 0; pp < 24; ++pp)
            __builtin_nontemporal_store(w[pp] * 0.03125f,
                                        yb + (32 * pp + g) * NSPAT);
    }
    __syncthreads();

    // ---------------- round 1: q = 24..31, 3-way split over p ---------------
    {
        const int q8    = g & 7;          // q - 24
        const int pbase = (g >> 3) * 8;   // 0 / 8 / 16 (wave-uniform)
        const float* p  = lds + q8 * STQ + ln;

        #pragma unroll
        for (int i = 0; i < 24; ++i)
            w[i] = p[i * STI];

        #pragma unroll
        for (int i = 0; i < 8; ++i) {
            float tt  = w[i];
            w[i]      = tt + w[i + 16];
            w[i + 16] = tt - w[i + 16];
        }
        #pragma unroll
        for (int i = 8; i < 16; ++i)
            w[i + 16] = w[i];

        FWHT_STAGE1(w, 8)
        FWHT_STAGE1(w, 4)
        FWHT_STAGE1(w, 2)
        FWHT_STAGE1(w, 1)

        const int q = 24 + q8;
        float* yb = y + base + ln;
        #pragma unroll
        for (int pp = 0; pp < 8; ++pp)
            __builtin_nontemporal_store(w[pbase + pp] * 0.03125f,
                                        yb + (32 * (pbase + pp) + q) * NSPAT);
    }
}

extern "C" void kernel_launch(void* const* d_in, const int* in_sizes, int n_in,
                              void* d_out, int out_size, void* d_ws, size_t ws_size,
                              hipStream_t stream) {
    const float* x = (const float*)d_in[0];
    float*       y = (float*)d_out;
    const int nblocks = 16 * (NSPAT / TS);   // 16 * 98 = 1568
    hadamard_c768_kernel<<<dim3(nblocks), dim3(768), 0, stream>>>(x, y);
}

// Round 6
// 298.698 us; speedup vs baseline: 1.0475x; 1.0475x over previous
//
#include <hip/hip_runtime.h>

// Hadamard transform along C of NCHW f32 tensor:
// y[b,:,s] = (H1024 @ pad1024(x[b,:,s]))[:768] / 32,  H1024 = H32 (x) H32, c = 32*i + j.
//
// v4: v3 hit 50% occupancy / 4.4 TB/s but spilled to scratch (WRITE_SIZE
// 533MB vs 151MB output) because 32 fully-unrolled loads with 64-bit
// per-load addresses need ~96 regs > the 85-reg cap of (768,6).
// Fixes: (1) uniform-base + uint offsets -> saddr form, 1 reg/address;
// (2) loads in two 16-batches split by sched_barrier(0) to cap live addrs;
// (3) no global store before any __syncthreads (each barrier drains
// vmcnt(0)) -> all stores issue after the last barrier, fire-and-forget.

#define NSPAT 3136            // 56*56
#define TS    32              // spatial tile per block
#define NBPB  98              // NSPAT / TS
#define STQ   33              // LDS q-stride (floats), odd
#define STI   793             // LDS i-stride (floats) = 24*STQ + 1, odd

// scalar float FWHT stage, 32-entry array
#define FWHT_STAGE1(arr, D)                                  \
    _Pragma("unroll")                                        \
    for (int _b = 0; _b < 32; _b += 2 * (D)) {               \
        _Pragma("unroll")                                    \
        for (int _k = 0; _k < (D); ++_k) {                   \
            float _t = arr[_b + _k];                         \
            arr[_b + _k]       = _t + arr[_b + _k + (D)];    \
            arr[_b + _k + (D)] = _t - arr[_b + _k + (D)];    \
        }                                                    \
    }

__global__ __launch_bounds__(768, 6)
void hadamard_c768_kernel(const float* __restrict__ x, float* __restrict__ y) {
    __shared__ float lds[24 * STI];   // 19032 floats = 76128 B

    const int t   = threadIdx.x;
    const int bid = blockIdx.x;
    const int b   = bid / NBPB;
    const int s0  = (bid % NBPB) * TS;
    const int base = b * 768 * NSPAT + s0;   // < 2^31

    const int g  = t >> 5;            // 0..23 : i-row (phase 1) / q (round 0)
    const int ln = t & 31;            // scalar lane along s

    const float* __restrict__ xb = x + base;   // wave/block-uniform base
    float*       __restrict__ yb = y + base;   // uniform base

    // ---------------- Phase 1: load + FWHT over j ---------------------------
    float a[32];
    const unsigned off0 = (unsigned)ln + (unsigned)(32 * g) * NSPAT;
    #pragma unroll
    for (int j = 0; j < 16; ++j)
        a[j] = xb[off0 + (unsigned)(j * NSPAT)];
    __builtin_amdgcn_sched_barrier(0);   // cap live address regs at ~16
    #pragma unroll
    for (int j = 16; j < 32; ++j)
        a[j] = xb[off0 + (unsigned)(j * NSPAT)];

    FWHT_STAGE1(a, 16)
    FWHT_STAGE1(a, 8)
    FWHT_STAGE1(a, 4)
    FWHT_STAGE1(a, 2)
    FWHT_STAGE1(a, 1)

    // ---------------- LDS round-0 write: q = 0..23 --------------------------
    float* pw = lds + g * STI + ln;
    #pragma unroll
    for (int q = 0; q < 24; ++q)
        pw[q * STQ] = a[q];
    __syncthreads();                      // B1: writes visible

    // round-0 read: thread owns q = g, spatial s = ln
    float w[32];
    {
        const float* pr = lds + g * STQ + ln;
        #pragma unroll
        for (int i = 0; i < 24; ++i)
            w[i] = pr[i * STI];
    }
    __syncthreads();                      // B2: all reads done, region reusable

    // round-1 write: q = 24..31 into slots 0..7 (a[] dead afterwards)
    #pragma unroll
    for (int q = 0; q < 8; ++q)
        pw[q * STQ] = a[24 + q];
    __syncthreads();                      // B3: last barrier; stores only below

    // ---------------- round 0: i-FWHT (rows 24..31 zero) + store ------------
    {
        #pragma unroll
        for (int i = 0; i < 8; ++i) {
            float tt  = w[i];
            w[i]      = tt + w[i + 16];
            w[i + 16] = tt - w[i + 16];
        }
        #pragma unroll
        for (int i = 8; i < 16; ++i)
            w[i + 16] = w[i];

        FWHT_STAGE1(w, 8)
        FWHT_STAGE1(w, 4)
        FWHT_STAGE1(w, 2)
        FWHT_STAGE1(w, 1)

        const unsigned oo = (unsigned)ln + (unsigned)g * NSPAT;  // c = 32*pp+g
        #pragma unroll
        for (int pp = 0; pp < 24; ++pp)
            __builtin_nontemporal_store(w[pp] * 0.03125f,
                                        yb + oo + (unsigned)(pp * 32 * NSPAT));
    }

    // ---------------- round 1: q = 24..31, 3-way split over p ---------------
    {
        const int q8    = g & 7;          // q - 24
        const int pbase = (g >> 3) * 8;   // 0 / 8 / 16 (wave-uniform)
        const float* pr = lds + q8 * STQ + ln;

        #pragma unroll
        for (int i = 0; i < 24; ++i)
            w[i] = pr[i * STI];

        #pragma unroll
        for (int i = 0; i < 8; ++i) {
            float tt  = w[i];
            w[i]      = tt + w[i + 16];
            w[i + 16] = tt - w[i + 16];
        }
        #pragma unroll
        for (int i = 8; i < 16; ++i)
            w[i + 16] = w[i];

        FWHT_STAGE1(w, 8)
        FWHT_STAGE1(w, 4)
        FWHT_STAGE1(w, 2)
        FWHT_STAGE1(w, 1)

        // c = 32*(pbase+pp) + 24 + q8
        const unsigned o1 = (unsigned)ln
                          + (unsigned)(24 + q8) * NSPAT
                          + (unsigned)(pbase * 32) * NSPAT;
        #pragma unroll
        for (int pp = 0; pp < 8; ++pp)
            __builtin_nontemporal_store(w[pbase + pp] * 0.03125f,
                                        yb + o1 + (unsigned)(pp * 32 * NSPAT));
    }
}

extern "C" void kernel_launch(void* const* d_in, const int* in_sizes, int n_in,
                              void* d_out, int out_size, void* d_ws, size_t ws_size,
                              hipStream_t stream) {
    const float* x = (const float*)d_in[0];
    float*       y = (float*)d_out;
    const int nblocks = 16 * NBPB;   // 1568
    hadamard_c768_kernel<<<dim3(nblocks), dim3(768), 0, stream>>>(x, y);
}

// Round 8
// 265.620 us; speedup vs baseline: 1.1779x; 1.1245x over previous
//
#include <hip/hip_runtime.h>

// Hadamard transform along C of NCHW f32 tensor:
// y[b,:,s] = (H1024 @ pad1024(x[b,:,s]))[:768] / 32,  H1024 = H32 (x) H32, c = 32*i + j.
//
// v5 (resubmit; round-7 bench was a broker timeout, kernel never ran):
// spill-free single-round redesign. v3/v4 (768 thr, 85-reg cap, 2 q-rounds)
// spilled ~250MB scratch because a[32] must outlive the first LDS round.
// Now: 1024 threads (32 groups x 32 scalar lanes), LDS holds ALL 32 q-slots
// (24 x 1057 floats = 101.5 KB, 1 block/CU, 16 waves = 50% occ), ONE barrier.
//   load (groups 0..23) -> j-FWHT -> LDS write -> barrier ->
//   LDS read (all 32 groups, q = g) -> zero-folded i-FWHT -> nt-stores (end).
// a[] dead at LDS write; w[] born after barrier; peak live ~70 < 128-reg cap
// of __launch_bounds__(1024,4). Odd strides (1057,33): every LDS access is
// 2-way-per-wave = free (m136). No store precedes any barrier.

#define NSPAT 3136            // 56*56
#define TS    32              // spatial tile per block
#define NBPB  98              // NSPAT / TS
#define STQ   33              // LDS q-stride (floats), odd
#define STI   1057            // LDS i-stride (floats) = 32*STQ + 1, odd

// scalar float FWHT stage, 32-entry array
#define FWHT_STAGE1(arr, D)                                  \
    _Pragma("unroll")                                        \
    for (int _b = 0; _b < 32; _b += 2 * (D)) {               \
        _Pragma("unroll")                                    \
        for (int _k = 0; _k < (D); ++_k) {                   \
            float _t = arr[_b + _k];                         \
            arr[_b + _k]       = _t + arr[_b + _k + (D)];    \
            arr[_b + _k + (D)] = _t - arr[_b + _k + (D)];    \
        }                                                    \
    }

__global__ __launch_bounds__(1024, 4)
void hadamard_c768_kernel(const float* __restrict__ x, float* __restrict__ y) {
    __shared__ float lds[24 * STI];   // 25368 floats = 101472 B

    const int t   = threadIdx.x;
    const int bid = blockIdx.x;
    const int b   = bid / NBPB;
    const int s0  = (bid % NBPB) * TS;
    const int base = b * 768 * NSPAT + s0;   // < 2^31

    const int g  = t >> 5;            // 0..31 : i-row (phase 1) / q (phase 2)
    const int ln = t & 31;            // scalar lane along s

    const float* __restrict__ xb = x + base;   // block-uniform base
    float*       __restrict__ yb = y + base;

    // ---------------- Phase 1: load + j-FWHT + LDS write (groups 0..23) -----
    if (g < 24) {                     // wave-uniform (g = 2w, 2w+1)
        float a[32];
        const unsigned off0 = (unsigned)ln + (unsigned)(32 * g) * NSPAT;
        #pragma unroll
        for (int j = 0; j < 32; ++j)
            a[j] = xb[off0 + (unsigned)(j * NSPAT)];

        FWHT_STAGE1(a, 16)
        FWHT_STAGE1(a, 8)
        FWHT_STAGE1(a, 4)
        FWHT_STAGE1(a, 2)
        FWHT_STAGE1(a, 1)

        float* pw = lds + g * STI + ln;
        #pragma unroll
        for (int q = 0; q < 32; ++q)
            pw[q * STQ] = a[q];
    }
    __syncthreads();                  // the only barrier

    // ---------------- Phase 2: i-FWHT (rows 24..31 zero) + store ------------
    {
        float w[32];
        const float* pr = lds + g * STQ + ln;   // q = g, s = ln
        #pragma unroll
        for (int i = 0; i < 24; ++i)
            w[i] = pr[i * STI];

        // stage d=16 with rows 24..31 known-zero
        #pragma unroll
        for (int i = 0; i < 8; ++i) {
            float tt  = w[i];
            w[i]      = tt + w[i + 16];
            w[i + 16] = tt - w[i + 16];
        }
        #pragma unroll
        for (int i = 8; i < 16; ++i)
            w[i + 16] = w[i];

        FWHT_STAGE1(w, 8)
        FWHT_STAGE1(w, 4)
        FWHT_STAGE1(w, 2)
        FWHT_STAGE1(w, 1)

        const unsigned oo = (unsigned)ln + (unsigned)g * NSPAT;  // c = 32*pp+g
        #pragma unroll
        for (int pp = 0; pp < 24; ++pp)
            __builtin_nontemporal_store(w[pp] * 0.03125f,
                                        yb + oo + (unsigned)(pp * 32 * NSPAT));
    }
}

extern "C" void kernel_launch(void* const* d_in, const int* in_sizes, int n_in,
                              void* d_out, int out_size, void* d_ws, size_t ws_size,
                              hipStream_t stream) {
    const float* x = (const float*)d_in[0];
    float*       y = (float*)d_out;
    const int nblocks = 16 * NBPB;   // 1568
    hadamard_c768_kernel<<<dim3(nblocks), dim3(1024), 0, stream>>>(x, y);
}